// Round 9
// baseline (193.369 us; speedup 1.0000x reference)
//
#include <hip/hip_runtime.h>

// GAT encoder: N=50000 nodes, E=800000 edges, H=4 heads, C=64 dims.
//
// R9 structure — coarse-bucket partition + split LDS aggregation, 7 dispatches:
//   hist    : per-block LDS 196-bin histogram of dst>>8 -> cnt[bucket][block];
//             per-block ea partial sums -> part
//   scan1/2/3: flat exclusive scan of cnt (612500 ints, bucket-major);
//             scan2 also reduces part -> meanea (single block, R6 pattern)
//   scatter : LDS returning cursors seeded from scan; write (src|eaq16,dst)
//   gat_edge: 8 sub-blocks per bucket (1568 x 256, 12KB LDS acc[256][12]);
//             each accumulates ~510 edges via ds_add_f32, dumps partial
//             coalesced to pacc[block][3072] (no global atomics)
//   combine : 16 lanes/node (R6 epilogue): sum 8 partials, self-loop,
//             W-epilogue, coalesced float4 stores
//
// R8 lesson (measured): 196-block gat = 31% occupancy, VALUBusy 5.8%, 83us —
// latency-bound; bucket count must not cap grid size. R7 lesson: device-scope
// float atomics are MEMORY-SIDE (32B/op, ~19G/s) — LDS only.
// History: R1 same-addr atomic 170us; R2 1-block scan 126us; R3 12-scalar
// factoring; R4 160.6us (44us harness ws poison = fixed cost); R5 FAILED
// (batched, replay-only divergence -> reverted); R6 162us; R7 597us; R8 193us.

#define N_NODES 50000
#define N_EDGES 800000
#define NBUK 196                    // buckets of 256 nodes
#define EBLK 3125                   // edge blocks = 800000/256 (exact)
#define SSPLIT 8                    // sub-blocks per bucket
#define GAT_BLKS (NBUK * SSPLIT)    // 1568
#define CNT_N (NBUK * EBLK)         // 612500
#define CNT4_N (CNT_N / 4)          // 153125 (exact)
#define SCAN_BLKS 599               // ceil(153125/256)

// ---- workspace layout (bytes) ----
constexpr size_t OFF_PART = 0;          // float[3125]
constexpr size_t OFF_BSUM = 12544;      // int[599]
constexpr size_t OFF_BOFF = 14976;      // int[599]
constexpr size_t OFF_MEAN = 17376;      // float[1]
constexpr size_t OFF_CNT  = 17408;      // int[612500], 16B aligned
constexpr size_t OFF_SORT = 2467456;    // int2[800000] -> ends 8867456
constexpr size_t OFF_PACC = 8867456;    // float[1568*3072] -> ends 28135040

// Fold att einsums into 20 per-head scalars in LDS (threads 0..255).
// sm[0..7]=ws(h,k) sm[8..15]=wd(h,k) sm[16..19]=we(h). No trailing sync.
__device__ __forceinline__ void fold_scal(const float* __restrict__ W,
                                          const float* __restrict__ att_src,
                                          const float* __restrict__ att_dst,
                                          const float* __restrict__ W_edge,
                                          const float* __restrict__ att_edge,
                                          float* sm) {
    int t = threadIdx.x;            // 0..255 = (h*64 + c)
    int h = t >> 6, lane = t & 63;
    float w0 = W[2 * t], w1 = W[2 * t + 1];
    float as = att_src[t], ad = att_dst[t];
    float ae = att_edge[t], wE = W_edge[t];
    float v0 = as * w0, v1 = as * w1, v2 = ad * w0, v3 = ad * w1, v4 = ae * wE;
    for (int off = 32; off; off >>= 1) {
        v0 += __shfl_down(v0, off, 64);
        v1 += __shfl_down(v1, off, 64);
        v2 += __shfl_down(v2, off, 64);
        v3 += __shfl_down(v3, off, 64);
        v4 += __shfl_down(v4, off, 64);
    }
    if (lane == 0) {
        sm[2 * h]     = v0;  sm[2 * h + 1] = v1;
        sm[8 + 2 * h] = v2;  sm[9 + 2 * h] = v3;
        sm[16 + h]    = v4;
    }
}

// Per-block LDS histogram of dst buckets + ea partial sums. No global atomics.
__global__ __launch_bounds__(256) void hist_kernel(const int* __restrict__ ei,
                                                   const float* __restrict__ ea,
                                                   int* __restrict__ cnt,
                                                   float* __restrict__ part) {
    __shared__ int hist[NBUK];
    __shared__ float red[4];
    int t = threadIdx.x;
    if (t < NBUK) hist[t] = 0;
    __syncthreads();
    int e = blockIdx.x * 256 + t;
    int dst = ei[N_EDGES + e];
    atomicAdd(&hist[dst >> 8], 1);
    float v = ea[e];
    for (int off = 32; off; off >>= 1) v += __shfl_down(v, off, 64);
    if ((t & 63) == 0) red[t >> 6] = v;
    __syncthreads();
    if (t < NBUK) cnt[t * EBLK + blockIdx.x] = hist[t];
    if (t == 0) part[blockIdx.x] = red[0] + red[1] + red[2] + red[3];
}

// Phase 1: in-place per-block exclusive scan of cnt (int4 per thread).
__global__ __launch_bounds__(256) void scan1_kernel(int4* __restrict__ cnt4,
                                                    int* __restrict__ bsum) {
    __shared__ int sm[4];
    int t = threadIdx.x, lane = t & 63, w = t >> 6;
    int gid = blockIdx.x * 256 + t;
    int4 d = make_int4(0, 0, 0, 0);
    if (gid < CNT4_N) d = cnt4[gid];
    int mysum = d.x + d.y + d.z + d.w;
    int s = mysum;
    for (int off = 1; off < 64; off <<= 1) {
        int v = __shfl_up(s, off, 64);
        if (lane >= off) s += v;
    }
    if (lane == 63) sm[w] = s;
    __syncthreads();
    int woff = 0;
    for (int i = 0; i < 4; ++i) if (i < w) woff += sm[i];
    int base = woff + s - mysum;
    if (gid < CNT4_N) {
        int4 r;
        r.x = base;
        r.y = r.x + d.x;
        r.z = r.y + d.y;
        r.w = r.z + d.z;
        cnt4[gid] = r;
    }
    if (t == 0) bsum[blockIdx.x] = sm[0] + sm[1] + sm[2] + sm[3];
}

// Phase 2: wave 0 scans the 599 block sums; all 256 threads reduce part.
__global__ __launch_bounds__(256) void scan2_kernel(const int* __restrict__ bsum,
                                                    const float* __restrict__ part,
                                                    int* __restrict__ boff,
                                                    float* __restrict__ meanp) {
    __shared__ float sf[4];
    int t = threadIdx.x, lane = t & 63;
    float v = 0.0f;
    for (int i = t; i < EBLK; i += 256) v += part[i];
    for (int off = 32; off; off >>= 1) v += __shfl_down(v, off, 64);
    if (lane == 0) sf[t >> 6] = v;
    __syncthreads();
    if (t == 0) *meanp = (sf[0] + sf[1] + sf[2] + sf[3]) * (1.0f / N_EDGES);

    if (t < 64) {
        int carry = 0;
        for (int it = 0; it < 10; ++it) {
            int i = it * 64 + lane;
            int x = (i < SCAN_BLKS) ? bsum[i] : 0;
            int s = x;
            for (int off = 1; off < 64; off <<= 1) {
                int y = __shfl_up(s, off, 64);
                if (lane >= off) s += y;
            }
            if (i < SCAN_BLKS) boff[i] = carry + s - x;
            carry += __shfl(s, 63, 64);
        }
    }
}

// Phase 3: add block offsets in place.
__global__ __launch_bounds__(256) void scan3_kernel(const int* __restrict__ boff,
                                                    int4* __restrict__ cnt4) {
    int gid = blockIdx.x * 256 + threadIdx.x;
    if (gid >= CNT4_N) return;
    int o = boff[blockIdx.x];
    int4 r = cnt4[gid];
    r.x += o; r.y += o; r.z += o; r.w += o;
    cnt4[gid] = r;
}

// Bucket scatter: LDS returning cursors (disjoint sub-ranges from the scan).
__global__ __launch_bounds__(256) void scatter_kernel(const int* __restrict__ ei,
                                                      const float* __restrict__ ea,
                                                      const int* __restrict__ scn,
                                                      int2* __restrict__ sorted) {
    __shared__ int cur[NBUK];
    int t = threadIdx.x;
    if (t < NBUK) cur[t] = scn[t * EBLK + blockIdx.x];
    __syncthreads();
    int e = blockIdx.x * 256 + t;
    int src = ei[e], dst = ei[N_EDGES + e];
    unsigned eaq = (unsigned)(ea[e] * 65535.0f + 0.5f);
    int pos = atomicAdd(&cur[dst >> 8], 1);
    sorted[pos] = make_int2(src | (int)(eaq << 16), dst);
}

// 8 sub-blocks per bucket (1568 x 256). LDS acc[256 nodes][12] via ds_add_f32;
// coalesced atomic-free dump to pacc[block][3072].
__global__ __launch_bounds__(256) void gat_edge_kernel(
        const float2* __restrict__ x2,
        const float* __restrict__ W, const float* __restrict__ att_src,
        const float* __restrict__ att_dst, const float* __restrict__ W_edge,
        const float* __restrict__ att_edge,
        const int* __restrict__ scn, const int2* __restrict__ sorted,
        float* __restrict__ pacc) {
    __shared__ float sm[24];
    __shared__ float acc[256 * 12];
    int t = threadIdx.x;
    fold_scal(W, att_src, att_dst, W_edge, att_edge, sm);
#pragma unroll
    for (int i = 0; i < 12; ++i) acc[t + 256 * i] = 0.0f;
    __syncthreads();

    float ws0[4], ws1[4], wd0[4], wd1[4], we[4];
#pragma unroll
    for (int h = 0; h < 4; ++h) {
        ws0[h] = sm[2 * h];     ws1[h] = sm[2 * h + 1];
        wd0[h] = sm[8 + 2 * h]; wd1[h] = sm[9 + 2 * h];
        we[h]  = sm[16 + h];
    }

    int b = blockIdx.x >> 3, s = blockIdx.x & 7;
    int start = scn[b * EBLK];
    int end = (b < NBUK - 1) ? scn[(b + 1) * EBLK] : N_EDGES;
    for (int i = start + s * 256 + t; i < end; i += SSPLIT * 256) {
        int2 p = sorted[i];
        int src = p.x & 0xffff;
        float eav = (float)((unsigned)p.x >> 16) * (1.0f / 65535.0f);
        int nlo = p.y & 255;
        float2 xs = x2[src], xd = x2[p.y];
        float* a = &acc[nlo * 12];
#pragma unroll
        for (int h = 0; h < 4; ++h) {
            float al = xs.x * ws0[h] + xs.y * ws1[h]
                     + xd.x * wd0[h] + xd.y * wd1[h] + eav * we[h];
            al = fmaxf(al, 0.2f * al);          // leaky_relu(0.2)
            float ex = __expf(al);
            unsafeAtomicAdd(a + h,     ex);         // D[h]   (ds_add_f32)
            unsafeAtomicAdd(a + 4 + h, ex * xs.x);  // Sx[h]
            unsafeAtomicAdd(a + 8 + h, ex * xs.y);  // Sy[h]
        }
    }
    __syncthreads();
    float* dst = pacc + (size_t)blockIdx.x * 3072;
#pragma unroll
    for (int i = 0; i < 12; ++i) dst[t + 256 * i] = acc[t + 256 * i];
}

// 16 lanes/node, 16 nodes/block, grid = 3125 (exact; 16-node chunk never
// spans a bucket). Sum 8 partials, self-loop, W-epilogue (R6/R8-proven).
__global__ __launch_bounds__(256) void combine_kernel(
        const float2* __restrict__ x2, const float4* __restrict__ W4,
        const float* __restrict__ W, const float* __restrict__ att_src,
        const float* __restrict__ att_dst, const float* __restrict__ W_edge,
        const float* __restrict__ att_edge,
        const float* __restrict__ pacc, const float* __restrict__ meanp,
        const float4* __restrict__ bias4, float4* __restrict__ out4) {
    __shared__ float sm[24];
    int t = threadIdx.x;
    fold_scal(W, att_src, att_dst, W_edge, att_edge, sm);
    __syncthreads();

    float meanea = *meanp;
    int grp = t >> 4, sub = t & 15;
    int node = blockIdx.x * 16 + grp;
    int b = node >> 8, nlo = node & 255;

    float val = 0.0f;
    if (sub < 12) {
        const float* p = pacc + (size_t)(b * SSPLIT) * 3072 + nlo * 12 + sub;
#pragma unroll
        for (int s = 0; s < SSPLIT; ++s) val += p[s * 3072];
    }
    float D[4], Sx[4], Sy[4];
#pragma unroll
    for (int h = 0; h < 4; ++h) {
        D[h]  = __shfl(val, h,     16);
        Sx[h] = __shfl(val, 4 + h, 16);
        Sy[h] = __shfl(val, 8 + h, 16);
    }

    float2 xd = x2[node];
#pragma unroll
    for (int h = 0; h < 4; ++h) {       // self loop (src=dst, ea=mean)
        float al = xd.x * (sm[2 * h] + sm[8 + 2 * h])
                 + xd.y * (sm[2 * h + 1] + sm[9 + 2 * h])
                 + meanea * sm[16 + h];
        al = fmaxf(al, 0.2f * al);
        float ex = __expf(al);
        D[h] += ex; Sx[h] += ex * xd.x; Sy[h] += ex * xd.y;
    }

#pragma unroll
    for (int k = 0; k < 4; ++k) {
        int j = sub + 16 * k;
        float invD = 1.0f / D[k];
        float4 wa = W4[2 * j], wb = W4[2 * j + 1], bb = bias4[j];
        float4 o;
        o.x = (wa.x * Sx[k] + wa.y * Sy[k]) * invD + bb.x;
        o.y = (wa.z * Sx[k] + wa.w * Sy[k]) * invD + bb.y;
        o.z = (wb.x * Sx[k] + wb.y * Sy[k]) * invD + bb.z;
        o.w = (wb.z * Sx[k] + wb.w * Sy[k]) * invD + bb.w;
        out4[node * 64 + j] = o;
    }
}

extern "C" void kernel_launch(void* const* d_in, const int* in_sizes, int n_in,
                              void* d_out, int out_size, void* d_ws, size_t ws_size,
                              hipStream_t stream) {
    const float* x        = (const float*)d_in[0];
    const int*   ei       = (const int*)  d_in[1];
    const float* ea       = (const float*)d_in[2];
    const float* W        = (const float*)d_in[3];
    const float* att_src  = (const float*)d_in[4];
    const float* att_dst  = (const float*)d_in[5];
    const float* W_edge   = (const float*)d_in[6];
    const float* att_edge = (const float*)d_in[7];
    const float* bias     = (const float*)d_in[8];

    char* ws = (char*)d_ws;
    float* part   = (float*)(ws + OFF_PART);
    int*   bsum   = (int*)  (ws + OFF_BSUM);
    int*   boff   = (int*)  (ws + OFF_BOFF);
    float* meanp  = (float*)(ws + OFF_MEAN);
    int*   cnt    = (int*)  (ws + OFF_CNT);
    int2*  sorted = (int2*) (ws + OFF_SORT);
    float* pacc   = (float*)(ws + OFF_PACC);

    hist_kernel<<<EBLK, 256, 0, stream>>>(ei, ea, cnt, part);
    scan1_kernel<<<SCAN_BLKS, 256, 0, stream>>>((int4*)cnt, bsum);
    scan2_kernel<<<1, 256, 0, stream>>>(bsum, part, boff, meanp);
    scan3_kernel<<<SCAN_BLKS, 256, 0, stream>>>(boff, (int4*)cnt);
    scatter_kernel<<<EBLK, 256, 0, stream>>>(ei, ea, cnt, sorted);
    gat_edge_kernel<<<GAT_BLKS, 256, 0, stream>>>(
        (const float2*)x, W, att_src, att_dst, W_edge, att_edge,
        cnt, sorted, pacc);
    combine_kernel<<<N_NODES / 16, 256, 0, stream>>>(
        (const float2*)x, (const float4*)W,
        W, att_src, att_dst, W_edge, att_edge,
        pacc, meanp, (const float4*)bias, (float4*)d_out);
}